// Round 23
// baseline (144.189 us; speedup 1.0000x reference)
//
#include <hip/hip_runtime.h>

#define N_ENT   100000
#define N_REL   500
#define N_EDGES 800000
#define DIM     128
#define WA_LD   384

#define MT       128                       // rows per ent block (4 waves x 32)
#define ENT_BLKS ((N_ENT + MT - 1) / MT)   // 782
#define REL_BLKS 125                       // 4 relations per block (4 waves)
#define CAP      64                        // bucket capacity (Poisson(8))

#define SCW 144                            // scratch stride (ushorts): row shift 8 banks

typedef __attribute__((ext_vector_type(8))) short  s8v;   // 8 bf16 / 8 ushort (16B)
typedef __attribute__((ext_vector_type(4))) float  f4v;   // MFMA acc

__device__ __forceinline__ unsigned short f2bf(float x) {
    unsigned u = __float_as_uint(x);
    return (unsigned short)((u + 0x7FFFu + ((u >> 16) & 1u)) >> 16);
}
__device__ __forceinline__ float bf2f(unsigned short h) {
    return __uint_as_float(((unsigned)h) << 16);
}

// ---------------------------------------------------------------------------
// K0: pre-convert [Wh | Wt] to bf16 in exact B-fragment order (16 blocks).
// B frag at lane l, elem e is B[kc*32 + (l>>4)*8 + e][nt*16 + (l&15)];
// stored at ((kc*16+nt)*64 + l)*8 + e.  (nt 0..7 = H table, 8..15 = T table)
__global__ __launch_bounds__(256) void k_prep(const float* __restrict__ Wa,
                                              short* __restrict__ Bg) {
    int idx = blockIdx.x * 256 + threadIdx.x;   // 0..4095
    int tt = idx >> 11;          // table 0/1
    int g = idx & 2047;
    int j = g >> 4;              // col within table
    int k8 = g & 15;             // 8-float k-granule
    const float* src = Wa + (size_t)j * WA_LD + tt * 256 + k8 * 8;
    float4 v0 = *(const float4*)src;
    float4 v1 = *(const float4*)(src + 4);
    float x[8] = {v0.x, v0.y, v0.z, v0.w, v1.x, v1.y, v1.z, v1.w};
    s8v hv;
#pragma unroll
    for (int e = 0; e < 8; ++e) hv[e] = (short)f2bf(x[e]);
    int col = tt * 128 + j;
    int kc = k8 >> 2;
    int lanep = (k8 & 3) * 16 + (col & 15);
    int nt = col >> 4;
    *(s8v*)&Bg[((size_t)((kc * 16 + nt) * 64 + lanep)) * 8] = hv;
}

// ---------------------------------------------------------------------------
// K1 (two-pass): blocks [0,782): 256 thr / 4 waves x 32 rows.
//   A fragments loaded ONCE into registers (Af[2][4], 8 upfront global loads);
//   pass 0 computes H (acc[2][8], B_H staged 32KB), pass 1 re-stages B_T and
//   computes T. Halved accumulators + 53KB LDS -> ~3 blocks/CU.
// blocks [782,907): rel projection PR (f32) + qr, 1 wave/relation.
__global__ __launch_bounds__(256) void k_fused(const float* __restrict__ ent,
                                               const short* __restrict__ Bg,
                                               const float* __restrict__ Wa2,
                                               unsigned short* __restrict__ PHb,
                                               unsigned short* __restrict__ PTb,
                                               float* __restrict__ qh,
                                               float* __restrict__ qt,
                                               const float* __restrict__ rel,
                                               const float* __restrict__ Wa,
                                               const float* __restrict__ ba,
                                               float* __restrict__ PR,
                                               float* __restrict__ qr) {
    __shared__ __align__(16) s8v Bs[2048];                     // 32 KB (one table)
    __shared__ __align__(16) unsigned short SCR[4 * 16 * SCW]; // 18.4 KB scratch
    __shared__ float relLds[4][128];                           // 2 KB
    int t = threadIdx.x;
    int wv = t >> 6;                 // wave 0..3
    int lane = t & 63;

    if (blockIdx.x >= ENT_BLKS) {
        int rb = blockIdx.x - ENT_BLKS;
        int r = rb * 4 + wv;
        if (r < N_REL) {
            relLds[wv][lane]      = rel[r * DIM + lane];
            relLds[wv][64 + lane] = rel[r * DIM + 64 + lane];
            int j0 = 2 * lane, j1 = j0 + 1;
            const float* w0 = Wa + (size_t)j0 * WA_LD + 128;
            const float* w1 = Wa + (size_t)j1 * WA_LD + 128;
            float a0 = ba[j0], a1 = ba[j1];
#pragma unroll 8
            for (int k4 = 0; k4 < 32; ++k4) {
                float4 rv = *(const float4*)&relLds[wv][4 * k4];
                float4 x0 = *(const float4*)&w0[4 * k4];
                float4 x1 = *(const float4*)&w1[4 * k4];
                a0 += rv.x * x0.x + rv.y * x0.y + rv.z * x0.z + rv.w * x0.w;
                a1 += rv.x * x1.x + rv.y * x1.y + rv.z * x1.z + rv.w * x1.w;
            }
            *(float2*)&PR[(size_t)r * DIM + j0] = make_float2(a0, a1);
            float p = a0 * Wa2[j0] + a1 * Wa2[j1];
#pragma unroll
            for (int m = 1; m <= 32; m <<= 1) p += __shfl_xor(p, m);
            if (lane == 0) qr[r] = p;
        }
        return;
    }

    // ---------------- ent path ----------------
    int l15 = lane & 15, lg = lane >> 4;
    int m0 = blockIdx.x * MT + wv * 32;

    // A -> registers upfront (8 parallel 32B loads, ent read once)
    s8v Af[2][4];
#pragma unroll
    for (int s = 0; s < 2; ++s) {
        int row = m0 + s * 16 + l15;
        if (row < N_ENT) {
            const float* ap = ent + (size_t)row * DIM + lg * 8;
#pragma unroll
            for (int kc = 0; kc < 4; ++kc) {
                float4 v0 = *(const float4*)(ap + kc * 32);
                float4 v1 = *(const float4*)(ap + kc * 32 + 4);
                float x[8] = {v0.x, v0.y, v0.z, v0.w, v1.x, v1.y, v1.z, v1.w};
#pragma unroll
                for (int e = 0; e < 8; ++e) Af[s][kc][e] = (short)f2bf(x[e]);
            }
        } else {
#pragma unroll
            for (int kc = 0; kc < 4; ++kc)
                Af[s][kc] = (s8v){0, 0, 0, 0, 0, 0, 0, 0};
        }
    }

    float wa2v[8];
#pragma unroll
    for (int c8 = 0; c8 < 8; ++c8) wa2v[c8] = Wa2[c8 * 16 + l15];

    const s8v* Bg8 = (const s8v*)Bg;
    unsigned short* scr = &SCR[wv * 16 * SCW];

#pragma unroll
    for (int pass = 0; pass < 2; ++pass) {
        // stage this table's B fragments (32 KB)
#pragma unroll
        for (int it = 0; it < 8; ++it) {
            int g = t + 256 * it;        // 0..2047
            int tile = g >> 6, l = g & 63;
            int kc = tile >> 3, ntl = tile & 7;
            Bs[g] = Bg8[(kc * 16 + pass * 8 + ntl) * 64 + l];
        }
        __syncthreads();                 // staging complete

        f4v acc[2][8];
#pragma unroll
        for (int s = 0; s < 2; ++s)
#pragma unroll
            for (int nt = 0; nt < 8; ++nt)
                acc[s][nt] = (f4v){0.f, 0.f, 0.f, 0.f};

#pragma unroll
        for (int kc = 0; kc < 4; ++kc)
#pragma unroll
            for (int nt = 0; nt < 8; ++nt) {
                s8v bg = Bs[(kc * 8 + nt) * 64 + lane];
                acc[0][nt] = __builtin_amdgcn_mfma_f32_16x16x32_bf16(Af[0][kc], bg, acc[0][nt], 0, 0, 0);
                acc[1][nt] = __builtin_amdgcn_mfma_f32_16x16x32_bf16(Af[1][kc], bg, acc[1][nt], 0, 0, 0);
            }
        __syncthreads();                 // all waves done reading Bs (safe restage)

        // q epilogue (this table's q) from acc regs
        float* qd = pass ? qt : qh;
        unsigned short* Pb = pass ? PTb : PHb;
#pragma unroll
        for (int s = 0; s < 2; ++s) {
            int rowb = m0 + s * 16 + lg * 4;
            float qp[4] = {0.f, 0.f, 0.f, 0.f};
#pragma unroll
            for (int nt = 0; nt < 8; ++nt)
#pragma unroll
                for (int g = 0; g < 4; ++g)
                    qp[g] += acc[s][nt][g] * wa2v[nt];
#pragma unroll
            for (int g = 0; g < 4; ++g) {
                float a = qp[g];
#pragma unroll
                for (int m = 1; m <= 8; m <<= 1) a += __shfl_xor(a, m);
                int row = rowb + g;
                if (l15 == 0 && row < N_ENT) qd[row] = a;
            }
        }

        // transpose/store via wave-private scratch -> coalesced 16B stores
#pragma unroll
        for (int s = 0; s < 2; ++s) {
#pragma unroll
            for (int nt = 0; nt < 8; ++nt)
#pragma unroll
                for (int g = 0; g < 4; ++g)
                    scr[(lg * 4 + g) * SCW + nt * 16 + l15] = f2bf(acc[s][nt][g]);
            // per-wave DS ops are in-order: reads below see writes above
#pragma unroll
            for (int p = 0; p < 4; ++p) {
                int c = p * 64 + lane;       // chunk 0..255
                int row16 = c >> 4, col8 = c & 15;
                s8v val = *(s8v*)&scr[row16 * SCW + col8 * 8];
                int row = m0 + s * 16 + row16;
                if (row < N_ENT)
                    *(s8v*)&Pb[(size_t)row * DIM + col8 * 8] = val;
            }
        }
    }
}

// ---------------------------------------------------------------------------
// K2: bucket scatter: w = exp(leaky(qh+qt+qr+ba2)); pos = cnt[h]++;
// pkw[h*CAP+pos] = {(r<<17)|t, w}. qr LDS-staged; trip LDS-coalesced.
__global__ __launch_bounds__(256) void k_scatter(const int* __restrict__ trip,
                                                 const float* __restrict__ qh,
                                                 const float* __restrict__ qt,
                                                 const float* __restrict__ qr,
                                                 const float* __restrict__ ba2,
                                                 int* __restrict__ cnt,
                                                 float2* __restrict__ pkw) {
    __shared__ int tl3[768];
    __shared__ float qrs[N_REL];
    int t = threadIdx.x;
    for (int i = t; i < N_REL; i += 256) qrs[i] = qr[i];
    int e0blk = blockIdx.x * 256;
    int base3 = e0blk * 3;
#pragma unroll
    for (int i = t; i < 768; i += 256)
        tl3[i] = (base3 + i < N_EDGES * 3) ? trip[base3 + i] : 0;
    __syncthreads();
    int e = e0blk + t;
    if (e >= N_EDGES) return;
    int h  = tl3[t * 3 + 0];
    int tt = tl3[t * 3 + 1];
    int r  = tl3[t * 3 + 2];
    float b = qh[h] + qt[tt] + qrs[r] + ba2[0];
    float lr = b > 0.f ? b : 0.01f * b;
    float w = expf(lr);
    int pos = atomicAdd(&cnt[h], 1);
    if (pos < CAP) {
        float2 v;
        v.x = __uint_as_float(((unsigned)r << 17) | (unsigned)tt);
        v.y = w;
        pkw[(size_t)h * CAP + pos] = v;
    }
}

// ---------------------------------------------------------------------------
// K3: per head (32 lanes, 2 heads/wave): acc = sum w*(PR[r]+PTb[t]);
// out = elu((acc+sw*PHb[h])/sw'). 4-deep unroll; PHb/PTb bf16, PR f32.
__global__ __launch_bounds__(256) void k_gather(const int* __restrict__ cnt,
                                                const float2* __restrict__ pkw,
                                                const unsigned short* __restrict__ PHb,
                                                const float* __restrict__ PR,
                                                const unsigned short* __restrict__ PTb,
                                                float* __restrict__ out) {
    int idx = blockIdx.x * 256 + threadIdx.x;
    int i = idx >> 5, lane = idx & 31;
    if (i >= N_ENT) return;
    int lane4 = lane * 4;
    int e0 = i * CAP;
    int n = cnt[i]; if (n > CAP) n = CAP;
    int e1 = e0 + n;
    float4 acc = make_float4(0.f, 0.f, 0.f, 0.f);
    float sw = 0.f;
    int e = e0;
    for (; e + 3 < e1; e += 4) {
        float2 pw0 = pkw[e],     pw1 = pkw[e + 1];
        float2 pw2 = pkw[e + 2], pw3 = pkw[e + 3];
        unsigned p0 = __float_as_uint(pw0.x), p1 = __float_as_uint(pw1.x);
        unsigned p2 = __float_as_uint(pw2.x), p3 = __float_as_uint(pw3.x);
        ushort4 b0 = *(const ushort4*)&PTb[(size_t)(p0 & 0x1FFFFu) * DIM + lane4];
        ushort4 b1 = *(const ushort4*)&PTb[(size_t)(p1 & 0x1FFFFu) * DIM + lane4];
        ushort4 b2 = *(const ushort4*)&PTb[(size_t)(p2 & 0x1FFFFu) * DIM + lane4];
        ushort4 b3 = *(const ushort4*)&PTb[(size_t)(p3 & 0x1FFFFu) * DIM + lane4];
        float4 r0 = *(const float4*)&PR[(size_t)(p0 >> 17) * DIM + lane4];
        float4 r1 = *(const float4*)&PR[(size_t)(p1 >> 17) * DIM + lane4];
        float4 r2 = *(const float4*)&PR[(size_t)(p2 >> 17) * DIM + lane4];
        float4 r3 = *(const float4*)&PR[(size_t)(p3 >> 17) * DIM + lane4];
        float w0 = pw0.y, w1 = pw1.y, w2 = pw2.y, w3 = pw3.y;
        acc.x += w0 * (r0.x + bf2f(b0.x)) + w1 * (r1.x + bf2f(b1.x))
               + w2 * (r2.x + bf2f(b2.x)) + w3 * (r3.x + bf2f(b3.x));
        acc.y += w0 * (r0.y + bf2f(b0.y)) + w1 * (r1.y + bf2f(b1.y))
               + w2 * (r2.y + bf2f(b2.y)) + w3 * (r3.y + bf2f(b3.y));
        acc.z += w0 * (r0.z + bf2f(b0.z)) + w1 * (r1.z + bf2f(b1.z))
               + w2 * (r2.z + bf2f(b2.z)) + w3 * (r3.z + bf2f(b3.z));
        acc.w += w0 * (r0.w + bf2f(b0.w)) + w1 * (r1.w + bf2f(b1.w))
               + w2 * (r2.w + bf2f(b2.w)) + w3 * (r3.w + bf2f(b3.w));
        sw += (w0 + w1) + (w2 + w3);
    }
    for (; e < e1; ++e) {
        float2 pw = pkw[e];
        unsigned p = __float_as_uint(pw.x);
        float w = pw.y;
        ushort4 b = *(const ushort4*)&PTb[(size_t)(p & 0x1FFFFu) * DIM + lane4];
        float4 pr = *(const float4*)&PR[(size_t)(p >> 17) * DIM + lane4];
        acc.x += w * (pr.x + bf2f(b.x));
        acc.y += w * (pr.y + bf2f(b.y));
        acc.z += w * (pr.z + bf2f(b.z));
        acc.w += w * (pr.w + bf2f(b.w));
        sw += w;
    }
    ushort4 hb = *(const ushort4*)&PHb[(size_t)i * DIM + lane4];
    acc.x += sw * bf2f(hb.x);
    acc.y += sw * bf2f(hb.y);
    acc.z += sw * bf2f(hb.z);
    acc.w += sw * bf2f(hb.w);
    float den = (sw == 0.f) ? 1e-12f : sw;
    float inv = 1.f / den;
    float vx = acc.x * inv, vy = acc.y * inv, vz = acc.z * inv, vw = acc.w * inv;
    vx = vx > 0.f ? vx : expm1f(vx);
    vy = vy > 0.f ? vy : expm1f(vy);
    vz = vz > 0.f ? vz : expm1f(vz);
    vw = vw > 0.f ? vw : expm1f(vw);
    *(float4*)&out[(size_t)i * DIM + lane4] = make_float4(vx, vy, vz, vw);
}

// ---------------------------------------------------------------------------
extern "C" void kernel_launch(void* const* d_in, const int* in_sizes, int n_in,
                              void* d_out, int out_size, void* d_ws, size_t ws_size,
                              hipStream_t stream) {
    const int*   trip = (const int*)d_in[0];
    const float* ent  = (const float*)d_in[1];
    const float* rel  = (const float*)d_in[2];
    const float* Wa   = (const float*)d_in[3];
    const float* ba   = (const float*)d_in[4];
    const float* Wa2  = (const float*)d_in[5];
    const float* ba2  = (const float*)d_in[6];
    float* out = (float*)d_out;

    float* ws = (float*)d_ws;
    size_t o = 0;
    unsigned short* PHb = (unsigned short*)(ws + o); o += (size_t)N_ENT * DIM / 2;
    unsigned short* PTb = (unsigned short*)(ws + o); o += (size_t)N_ENT * DIM / 2;
    float* PR = ws + o;        o += (size_t)N_REL * DIM;
    float* qh = ws + o;        o += N_ENT;
    float* qt = ws + o;        o += N_ENT;
    float* qr = ws + o;        o += N_REL + 4;
    short* Bg = (short*)(ws + o);     o += 32768 / 2 + 8;
    int*   cnt = (int*)(ws + o);      o += N_ENT;
    float2* pkw = (float2*)(ws + o);  o += (size_t)N_ENT * CAP * 2;

    hipMemsetAsync(cnt, 0, (size_t)N_ENT * sizeof(int), stream);

    k_prep<<<16, 256, 0, stream>>>(Wa, Bg);
    k_fused<<<ENT_BLKS + REL_BLKS, 256, 0, stream>>>(ent, Bg, Wa2, PHb, PTb, qh, qt,
                                                     rel, Wa, ba, PR, qr);
    k_scatter<<<(N_EDGES + 255) / 256, 256, 0, stream>>>(trip, qh, qt, qr, ba2, cnt, pkw);
    k_gather<<<(N_ENT * 32) / 256, 256, 0, stream>>>(cnt, pkw, PHb, PR, PTb, out);
}

// Round 24
// 137.320 us; speedup vs baseline: 1.0500x; 1.0500x over previous
//
#include <hip/hip_runtime.h>

#define N_ENT   100000
#define N_REL   500
#define N_EDGES 800000
#define DIM     128
#define WA_LD   384

#define MT       256
#define ENT_BLKS ((N_ENT + MT - 1) / MT)   // 391
#define REL_BLKS 63                        // 8 relations per block (8 waves)
#define CAP      64                        // bucket capacity (Poisson(8): P(deg>64)~1e-30)

// transpose scratch stride (ushorts)
#define SCW 264

typedef __attribute__((ext_vector_type(8))) short  s8v;   // 8 bf16 / 8 ushort (16B)
typedef __attribute__((ext_vector_type(4))) float  f4v;   // MFMA acc

__device__ __forceinline__ unsigned short f2bf(float x) {
    unsigned u = __float_as_uint(x);
    return (unsigned short)((u + 0x7FFFu + ((u >> 16) & 1u)) >> 16);
}
__device__ __forceinline__ float bf2f(unsigned short h) {
    return __uint_as_float(((unsigned)h) << 16);
}

// ---------------------------------------------------------------------------
// K0: pre-convert [Wh | Wt] to bf16 in exact B-fragment order (16 blocks).
__global__ __launch_bounds__(256) void k_prep(const float* __restrict__ Wa,
                                              short* __restrict__ Bg) {
    int idx = blockIdx.x * 256 + threadIdx.x;   // 0..4095
    int tt = idx >> 11;          // table 0/1
    int g = idx & 2047;
    int j = g >> 4;              // col within table
    int k8 = g & 15;             // 8-float k-granule
    const float* src = Wa + (size_t)j * WA_LD + tt * 256 + k8 * 8;
    float4 v0 = *(const float4*)src;
    float4 v1 = *(const float4*)(src + 4);
    float x[8] = {v0.x, v0.y, v0.z, v0.w, v1.x, v1.y, v1.z, v1.w};
    s8v hv;
#pragma unroll
    for (int e = 0; e < 8; ++e) hv[e] = (short)f2bf(x[e]);
    int col = tt * 128 + j;
    int kc = k8 >> 2;
    int lanep = (k8 & 3) * 16 + (col & 15);
    int nt = col >> 4;
    *(s8v*)&Bg[((size_t)((kc * 16 + nt) * 64 + lanep)) * 8] = hv;
}

// ---------------------------------------------------------------------------
// K1: blocks [0,391): 512 thr / 8 waves x 32 rows: MFMA projection -> PHb+PTb
//   (bf16, coalesced via LDS transpose) + fused qh/qt.
// blocks [391,454): rel projection PR (f32) + qr, 1 wave/relation.
__global__ __launch_bounds__(512) void k_fused(const float* __restrict__ ent,
                                               const short* __restrict__ Bg,
                                               const float* __restrict__ Wa2,
                                               unsigned short* __restrict__ PHb,
                                               unsigned short* __restrict__ PTb,
                                               float* __restrict__ qh,
                                               float* __restrict__ qt,
                                               const float* __restrict__ rel,
                                               const float* __restrict__ Wa,
                                               const float* __restrict__ ba,
                                               float* __restrict__ PR,
                                               float* __restrict__ qr) {
    __shared__ __align__(16) unsigned short SCR[8 * 16 * SCW];
    __shared__ float relLds[8][128];
    s8v* BsV = (s8v*)SCR;
    int t = threadIdx.x;
    int wv = t >> 6;                 // wave 0..7
    int lane = t & 63;

    if (blockIdx.x >= ENT_BLKS) {
        int rb = blockIdx.x - ENT_BLKS;
        int r = rb * 8 + wv;
        if (r < N_REL) {
            relLds[wv][lane]      = rel[r * DIM + lane];
            relLds[wv][64 + lane] = rel[r * DIM + 64 + lane];
            int j0 = 2 * lane, j1 = j0 + 1;
            const float* w0 = Wa + (size_t)j0 * WA_LD + 128;
            const float* w1 = Wa + (size_t)j1 * WA_LD + 128;
            float a0 = ba[j0], a1 = ba[j1];
#pragma unroll 8
            for (int k4 = 0; k4 < 32; ++k4) {
                float4 rv = *(const float4*)&relLds[wv][4 * k4];
                float4 x0 = *(const float4*)&w0[4 * k4];
                float4 x1 = *(const float4*)&w1[4 * k4];
                a0 += rv.x * x0.x + rv.y * x0.y + rv.z * x0.z + rv.w * x0.w;
                a1 += rv.x * x1.x + rv.y * x1.y + rv.z * x1.z + rv.w * x1.w;
            }
            *(float2*)&PR[(size_t)r * DIM + j0] = make_float2(a0, a1);
            float p = a0 * Wa2[j0] + a1 * Wa2[j1];
#pragma unroll
            for (int m = 1; m <= 32; m <<= 1) p += __shfl_xor(p, m);
            if (lane == 0) qr[r] = p;
        }
        return;
    }

    // ---------------- ent path ----------------
#pragma unroll
    for (int it = 0; it < 8; ++it) {
        int idx = t + 512 * it;      // 0..4095
        BsV[idx] = *(const s8v*)&Bg[(size_t)idx * 8];
    }

    int l15 = lane & 15, lg = lane >> 4;
    int m0 = blockIdx.x * MT + wv * 32;

    f4v acc[2][16];
#pragma unroll
    for (int s = 0; s < 2; ++s)
#pragma unroll
        for (int nt = 0; nt < 16; ++nt)
            acc[s][nt] = (f4v){0.f, 0.f, 0.f, 0.f};

    __syncthreads();

#pragma unroll
    for (int kc = 0; kc < 4; ++kc) {
        s8v Ah[2];
#pragma unroll
        for (int s = 0; s < 2; ++s) {
            int row = m0 + s * 16 + l15;
            if (row < N_ENT) {
                const float* ap = ent + (size_t)row * DIM + kc * 32 + lg * 8;
                float4 v0 = *(const float4*)ap;
                float4 v1 = *(const float4*)(ap + 4);
                float x[8] = {v0.x, v0.y, v0.z, v0.w, v1.x, v1.y, v1.z, v1.w};
#pragma unroll
                for (int e = 0; e < 8; ++e) Ah[s][e] = (short)f2bf(x[e]);
            } else {
                Ah[s] = (s8v){0, 0, 0, 0, 0, 0, 0, 0};
            }
        }
#pragma unroll
        for (int nt = 0; nt < 16; ++nt) {
            s8v bg = BsV[(kc * 16 + nt) * 64 + lane];
            acc[0][nt] = __builtin_amdgcn_mfma_f32_16x16x32_bf16(Ah[0], bg, acc[0][nt], 0, 0, 0);
            acc[1][nt] = __builtin_amdgcn_mfma_f32_16x16x32_bf16(Ah[1], bg, acc[1][nt], 0, 0, 0);
        }
    }

    // fused q = P . Wa2 from acc regs
    float wa2v[8];
#pragma unroll
    for (int c8 = 0; c8 < 8; ++c8) wa2v[c8] = Wa2[c8 * 16 + l15];

#pragma unroll
    for (int s = 0; s < 2; ++s) {
        int rowb = m0 + s * 16 + lg * 4;
        float qhp[4] = {0.f, 0.f, 0.f, 0.f};
        float qtp[4] = {0.f, 0.f, 0.f, 0.f};
#pragma unroll
        for (int nt = 0; nt < 16; ++nt) {
#pragma unroll
            for (int g = 0; g < 4; ++g) {
                float v = acc[s][nt][g];
                if (nt < 8) qhp[g] += v * wa2v[nt];
                else        qtp[g] += v * wa2v[nt & 7];
            }
        }
#pragma unroll
        for (int g = 0; g < 4; ++g) {
            float a = qhp[g], b = qtp[g];
#pragma unroll
            for (int m = 1; m <= 8; m <<= 1) {
                a += __shfl_xor(a, m);
                b += __shfl_xor(b, m);
            }
            int row = rowb + g;
            if (l15 == 0 && row < N_ENT) { qh[row] = a; qt[row] = b; }
        }
    }

    __syncthreads();   // all waves done with B LDS before scratch reuse

    // epilogue: per-wave LDS transpose -> coalesced 16B stores
    unsigned short* scr = &SCR[wv * 16 * SCW];
#pragma unroll
    for (int s = 0; s < 2; ++s) {
#pragma unroll
        for (int nt = 0; nt < 16; ++nt)
#pragma unroll
            for (int g = 0; g < 4; ++g)
                scr[(lg * 4 + g) * SCW + nt * 16 + l15] = f2bf(acc[s][nt][g]);
#pragma unroll
        for (int p = 0; p < 8; ++p) {
            int row16 = p * 2 + (lane >> 5);
            int col8  = lane & 31;
            s8v val = *(s8v*)&scr[row16 * SCW + col8 * 8];
            int row = m0 + s * 16 + row16;
            if (row < N_ENT) {
                unsigned short* dst = (col8 < 16 ? PHb : PTb)
                                    + (size_t)row * DIM + (col8 & 15) * 8;
                *(s8v*)dst = val;
            }
        }
    }
}

// ---------------------------------------------------------------------------
// K2: bucket scatter: w = exp(leaky(qh+qt+qr+ba2)); pos = cnt[h]++;
// pkw[h*CAP+pos] = {(r<<17)|t, w}. qr LDS-staged; trip LDS-coalesced.
__global__ __launch_bounds__(256) void k_scatter(const int* __restrict__ trip,
                                                 const float* __restrict__ qh,
                                                 const float* __restrict__ qt,
                                                 const float* __restrict__ qr,
                                                 const float* __restrict__ ba2,
                                                 int* __restrict__ cnt,
                                                 float2* __restrict__ pkw) {
    __shared__ int tl3[768];
    __shared__ float qrs[N_REL];
    int t = threadIdx.x;
    for (int i = t; i < N_REL; i += 256) qrs[i] = qr[i];
    int e0blk = blockIdx.x * 256;
    int base3 = e0blk * 3;
#pragma unroll
    for (int i = t; i < 768; i += 256)
        tl3[i] = (base3 + i < N_EDGES * 3) ? trip[base3 + i] : 0;
    __syncthreads();
    int e = e0blk + t;
    if (e >= N_EDGES) return;
    int h  = tl3[t * 3 + 0];
    int tt = tl3[t * 3 + 1];
    int r  = tl3[t * 3 + 2];
    float b = qh[h] + qt[tt] + qrs[r] + ba2[0];
    float lr = b > 0.f ? b : 0.01f * b;
    float w = expf(lr);
    int pos = atomicAdd(&cnt[h], 1);
    if (pos < CAP) {
        float2 v;
        v.x = __uint_as_float(((unsigned)r << 17) | (unsigned)tt);
        v.y = w;
        pkw[(size_t)h * CAP + pos] = v;
    }
}

// ---------------------------------------------------------------------------
// K3: per head (32 lanes, 2 heads/wave): acc = sum w*(PR[r]+PTb[t]);
// out = elu((acc+sw*PHb[h])/sw'). 4-deep unroll; PHb/PTb bf16, PR f32.
__global__ __launch_bounds__(256) void k_gather(const int* __restrict__ cnt,
                                                const float2* __restrict__ pkw,
                                                const unsigned short* __restrict__ PHb,
                                                const float* __restrict__ PR,
                                                const unsigned short* __restrict__ PTb,
                                                float* __restrict__ out) {
    int idx = blockIdx.x * 256 + threadIdx.x;
    int i = idx >> 5, lane = idx & 31;
    if (i >= N_ENT) return;
    int lane4 = lane * 4;
    int e0 = i * CAP;
    int n = cnt[i]; if (n > CAP) n = CAP;
    int e1 = e0 + n;
    float4 acc = make_float4(0.f, 0.f, 0.f, 0.f);
    float sw = 0.f;
    int e = e0;
    for (; e + 3 < e1; e += 4) {
        float2 pw0 = pkw[e],     pw1 = pkw[e + 1];
        float2 pw2 = pkw[e + 2], pw3 = pkw[e + 3];
        unsigned p0 = __float_as_uint(pw0.x), p1 = __float_as_uint(pw1.x);
        unsigned p2 = __float_as_uint(pw2.x), p3 = __float_as_uint(pw3.x);
        ushort4 b0 = *(const ushort4*)&PTb[(size_t)(p0 & 0x1FFFFu) * DIM + lane4];
        ushort4 b1 = *(const ushort4*)&PTb[(size_t)(p1 & 0x1FFFFu) * DIM + lane4];
        ushort4 b2 = *(const ushort4*)&PTb[(size_t)(p2 & 0x1FFFFu) * DIM + lane4];
        ushort4 b3 = *(const ushort4*)&PTb[(size_t)(p3 & 0x1FFFFu) * DIM + lane4];
        float4 r0 = *(const float4*)&PR[(size_t)(p0 >> 17) * DIM + lane4];
        float4 r1 = *(const float4*)&PR[(size_t)(p1 >> 17) * DIM + lane4];
        float4 r2 = *(const float4*)&PR[(size_t)(p2 >> 17) * DIM + lane4];
        float4 r3 = *(const float4*)&PR[(size_t)(p3 >> 17) * DIM + lane4];
        float w0 = pw0.y, w1 = pw1.y, w2 = pw2.y, w3 = pw3.y;
        acc.x += w0 * (r0.x + bf2f(b0.x)) + w1 * (r1.x + bf2f(b1.x))
               + w2 * (r2.x + bf2f(b2.x)) + w3 * (r3.x + bf2f(b3.x));
        acc.y += w0 * (r0.y + bf2f(b0.y)) + w1 * (r1.y + bf2f(b1.y))
               + w2 * (r2.y + bf2f(b2.y)) + w3 * (r3.y + bf2f(b3.y));
        acc.z += w0 * (r0.z + bf2f(b0.z)) + w1 * (r1.z + bf2f(b1.z))
               + w2 * (r2.z + bf2f(b2.z)) + w3 * (r3.z + bf2f(b3.z));
        acc.w += w0 * (r0.w + bf2f(b0.w)) + w1 * (r1.w + bf2f(b1.w))
               + w2 * (r2.w + bf2f(b2.w)) + w3 * (r3.w + bf2f(b3.w));
        sw += (w0 + w1) + (w2 + w3);
    }
    for (; e < e1; ++e) {
        float2 pw = pkw[e];
        unsigned p = __float_as_uint(pw.x);
        float w = pw.y;
        ushort4 b = *(const ushort4*)&PTb[(size_t)(p & 0x1FFFFu) * DIM + lane4];
        float4 pr = *(const float4*)&PR[(size_t)(p >> 17) * DIM + lane4];
        acc.x += w * (pr.x + bf2f(b.x));
        acc.y += w * (pr.y + bf2f(b.y));
        acc.z += w * (pr.z + bf2f(b.z));
        acc.w += w * (pr.w + bf2f(b.w));
        sw += w;
    }
    ushort4 hb = *(const ushort4*)&PHb[(size_t)i * DIM + lane4];
    acc.x += sw * bf2f(hb.x);
    acc.y += sw * bf2f(hb.y);
    acc.z += sw * bf2f(hb.z);
    acc.w += sw * bf2f(hb.w);
    float den = (sw == 0.f) ? 1e-12f : sw;
    float inv = 1.f / den;
    float vx = acc.x * inv, vy = acc.y * inv, vz = acc.z * inv, vw = acc.w * inv;
    vx = vx > 0.f ? vx : expm1f(vx);
    vy = vy > 0.f ? vy : expm1f(vy);
    vz = vz > 0.f ? vz : expm1f(vz);
    vw = vw > 0.f ? vw : expm1f(vw);
    *(float4*)&out[(size_t)i * DIM + lane4] = make_float4(vx, vy, vz, vw);
}

// ---------------------------------------------------------------------------
extern "C" void kernel_launch(void* const* d_in, const int* in_sizes, int n_in,
                              void* d_out, int out_size, void* d_ws, size_t ws_size,
                              hipStream_t stream) {
    const int*   trip = (const int*)d_in[0];
    const float* ent  = (const float*)d_in[1];
    const float* rel  = (const float*)d_in[2];
    const float* Wa   = (const float*)d_in[3];
    const float* ba   = (const float*)d_in[4];
    const float* Wa2  = (const float*)d_in[5];
    const float* ba2  = (const float*)d_in[6];
    float* out = (float*)d_out;

    float* ws = (float*)d_ws;
    size_t o = 0;
    unsigned short* PHb = (unsigned short*)(ws + o); o += (size_t)N_ENT * DIM / 2;
    unsigned short* PTb = (unsigned short*)(ws + o); o += (size_t)N_ENT * DIM / 2;
    float* PR = ws + o;        o += (size_t)N_REL * DIM;
    float* qh = ws + o;        o += N_ENT;
    float* qt = ws + o;        o += N_ENT;
    float* qr = ws + o;        o += N_REL + 4;
    short* Bg = (short*)(ws + o);     o += 32768 / 2 + 8;
    int*   cnt = (int*)(ws + o);      o += N_ENT;
    float2* pkw = (float2*)(ws + o);  o += (size_t)N_ENT * CAP * 2;

    hipMemsetAsync(cnt, 0, (size_t)N_ENT * sizeof(int), stream);

    k_prep<<<16, 256, 0, stream>>>(Wa, Bg);
    k_fused<<<ENT_BLKS + REL_BLKS, 512, 0, stream>>>(ent, Bg, Wa2, PHb, PTb, qh, qt,
                                                     rel, Wa, ba, PR, qr);
    k_scatter<<<(N_EDGES + 255) / 256, 256, 0, stream>>>(trip, qh, qt, qr, ba2, cnt, pkw);
    k_gather<<<(N_ENT * 32) / 256, 256, 0, stream>>>(cnt, pkw, PHb, PR, PTb, out);
}